// Round 5
// baseline (258.956 us; speedup 1.0000x reference)
//
#include <hip/hip_runtime.h>
#include <cstdint>

// Chamfer distance, B=8, N=M=4096, D=128, f32 in, scalar f32 out.
// R17: dispatch-count attack with only harness-proven pieces.
// Ledger: ~15us overhead PER DISPATCH (R12: 121.6 total vs ~69 kernel;
// R16: 142.6 vs ~100). So: 2 dispatches total.
//  - prep_y: y->bf16 + y^2 + seed minbuf(rowmin++colmin)=INF + counter=0.
//  - chamfer: R12's EXACT main loop (gld16 staging, interleaved bfr reads,
//    no hoist/setprio -- those cost 6.5us in R14) + R16's proven x-prologue
//    (per-block f32->bf16 afrag + x2 via shfl, 8x redundant, off-loop) +
//    R13's proven atomicMin min-epilogue (isolated cost only +2.4us =
//    R13 55.6 vs R14 53.2, same confounds) -> cminW LDS gone (32KB total),
//    partials shrink 3MB->256KB -> fence+counter; LAST block reduces 256KB
//    with device-scope loads and plain-stores out (harness pre-zeroes out).
// No grid.sync, no spin: single atomicAdd per block, last finisher reduces.
// Workspace: yb(8M) y2(128K) minbuf(256K) counter(4B).

#define B_   8
#define N_   4096
#define M_   4096
#define D_   128
#define TPB  8               // y-tiles (64 cols) per block -> 512-col chunk
#define ROWS_PB 256          // x-rows per block = 4 waves * 64
#define XG   (N_ / ROWS_PB)  // 16 x-groups
#define CHUNKS (M_ / (TPB * 64))   // 8 y-chunks
#define GRID (B_ * XG * CHUNKS)    // 1024 blocks

typedef __bf16 bf16x8 __attribute__((ext_vector_type(8)));
typedef float  f32x4  __attribute__((ext_vector_type(4)));
typedef unsigned int u32;

static __device__ __forceinline__ unsigned short f2bf(float f) {
  unsigned u = __float_as_uint(f);
  u += 0x7FFFu + ((u >> 16) & 1u);   // round-to-nearest-even
  return (unsigned short)(u >> 16);
}
static __device__ __forceinline__ u32 pk2(float a, float b) {
  return (u32)f2bf(a) | ((u32)f2bf(b) << 16);
}
static __device__ __forceinline__ void gld16(void* lds, const void* g) {
  __builtin_amdgcn_global_load_lds(
      (const __attribute__((address_space(1))) void*)g,
      (__attribute__((address_space(3))) void*)lds, 16, 0, 0);
}

// prep_y: wave handles 2 y-rows (32 lanes x float4). yb = bf16(y), y2 fp32.
// Also: minbuf[0..2*B*N) = +INF (rowmin ++ colmin), *counter = 0.
__global__ __launch_bounds__(256) void prep_y(
    const float* __restrict__ y, unsigned short* __restrict__ yb,
    float* __restrict__ y2, float* __restrict__ minbuf, int* __restrict__ counter)
{
  const int flat = blockIdx.x * 256 + threadIdx.x;
  if (flat < 2 * B_ * N_) minbuf[flat] = __uint_as_float(0x7F800000u);
  if (flat == 0) *counter = 0;

  int gw   = flat >> 6;                      // wave id 0..16383
  int lane = threadIdx.x & 63;
  int half = lane >> 5, sub = lane & 31;
  int row  = gw * 2 + half;                  // 0 .. B*M-1
  size_t base = (size_t)row * D_ + sub * 4;
  float4 v = *(const float4*)(y + base);
  u32 p0 = pk2(v.x, v.y);
  u32 p1 = pk2(v.z, v.w);
  *(uint2*)(yb + base) = make_uint2(p0, p1);
  float s = v.x * v.x + v.y * v.y + v.z * v.z + v.w * v.w;
  #pragma unroll
  for (int m = 1; m < 32; m <<= 1) s += __shfl_xor(s, m, 64);
  if (sub == 0) y2[row] = s;
}

// Fragment layouts (HW-verified):
//   A/B operand: lane holds elems [row=lane&15][k=(lane>>4)*8 + 0..7]
//   C/D:         lane reg r holds [row=(lane>>4)*4+r][col=lane&15]
// acc init = x2_i (afrag holds bf16(-2x)), so a = x2_i - 2<x,y>; s = a + y2_j.
// LDS y layout: row r (256B), logical 16B-chunk c at physical chunk c^(r&15).
__global__ __launch_bounds__(256) void chamfer(
    const float* __restrict__ x, const unsigned short* __restrict__ yb,
    const float* __restrict__ y2, float* __restrict__ minbuf,
    int* __restrict__ counter, float* __restrict__ out)
{
  __shared__ unsigned short ys[2 * 8192];    // two 16 KB swizzled y-tiles ONLY
  __shared__ int amLast;
  __shared__ float red[4];

  float* rowmin = minbuf;                    // [B*N]
  float* colmin = minbuf + B_ * N_;          // [B*M]

  const int tid  = threadIdx.x;
  const int wave = tid >> 6;                 // 0..3
  const int lane = tid & 63;
  const int quad = lane >> 4;
  const int l15  = lane & 15;

  const int id    = blockIdx.x;        // 0..1023
  const int b     = id & 7;
  const int xg    = (id >> 3) & 15;
  const int chunk = id >> 7;           // 0..7
  const int n0    = xg * ROWS_PB;
  const int mc0   = chunk * (TPB * 64);

  // DMA: 16KB tile, 4 gld16/lane: instr i covers bytes (wave*4+i)*1024+lane*16.
  int srcoff[4], ldsoff[4];
  #pragma unroll
  for (int i = 0; i < 4; ++i) {
    int p  = (wave * 4 + i) * 1024 + lane * 16;
    int r  = p >> 8;                 // y row 0..63
    int pc = (p >> 4) & 15;          // physical chunk
    int c  = pc ^ (r & 15);          // logical chunk
    srcoff[i] = r * D_ + c * 8;      // elements
    ldsoff[i] = (wave * 4 + i) * 1024;
  }

  // preload tile 0
  {
    const unsigned short* src = yb + ((size_t)b * M_ + mc0) * D_;
    #pragma unroll
    for (int i = 0; i < 4; ++i) gld16((char*)ys + ldsoff[i], src + srcoff[i]);
  }

  // prologue: x panel f32 -> afrag(bf16 of -2x) + x2 via quad folds (R16-proven)
  bf16x8 afrag[4][4];   // [kb][rt]
  f32x4 xvv[4];
  {
    float x2row[4];
    #pragma unroll
    for (int rt = 0; rt < 4; ++rt) {
      const float* xs = x + (size_t)(b * N_ + n0 + wave * 64 + rt * 16 + l15) * D_ + quad * 8;
      float p = 0.0f;
      #pragma unroll
      for (int kb = 0; kb < 4; ++kb) {
        float4 u0 = *(const float4*)(xs + kb * 32);
        float4 u1 = *(const float4*)(xs + kb * 32 + 4);
        p += u0.x*u0.x + u0.y*u0.y + u0.z*u0.z + u0.w*u0.w
           + u1.x*u1.x + u1.y*u1.y + u1.z*u1.z + u1.w*u1.w;
        union { u32 w[4]; bf16x8 v; } tt;
        tt.w[0] = pk2(-2.f*u0.x, -2.f*u0.y);
        tt.w[1] = pk2(-2.f*u0.z, -2.f*u0.w);
        tt.w[2] = pk2(-2.f*u1.x, -2.f*u1.y);
        tt.w[3] = pk2(-2.f*u1.z, -2.f*u1.w);
        afrag[kb][rt] = tt.v;
      }
      p += __shfl_xor(p, 16, 64);    // fold the 4 quads holding this row
      p += __shfl_xor(p, 32, 64);
      x2row[rt] = p;                 // = x2 of row rt*16 + l15
    }
    // redistribute to C/D layout: lane reg r needs row quad*4 + r
    #pragma unroll
    for (int rt = 0; rt < 4; ++rt)
      #pragma unroll
      for (int r = 0; r < 4; ++r)
        xvv[rt][r] = __shfl(x2row[rt], quad * 4 + r, 16);
  }

  const float FINF = __uint_as_float(0x7F800000u);
  float rmin2[4][4];
  #pragma unroll
  for (int rt = 0; rt < 4; ++rt)
    #pragma unroll
    for (int r = 0; r < 4; ++r) rmin2[rt][r] = FINF;

  #pragma unroll 1
  for (int t = 0; t < TPB; ++t) {
    const int m0 = mc0 + t * 64;
    const int d  = (t & 1) * 16384;    // current buffer byte offset
    __syncthreads();  // drains DMA for buf d (prefetch had a full iteration);
                      // fences prior-buffer reads

    if (t + 1 < TPB) {  // prefetch next tile into the other buffer ASAP
      const unsigned short* src = yb + ((size_t)b * M_ + m0 + 64) * D_;
      char* dst = (char*)ys + (16384 - d);
      #pragma unroll
      for (int i = 0; i < 4; ++i) gld16(dst + ldsoff[i], src + srcoff[i]);
    }

    // per-tile y^2: 4 per-lane scalars (16-lane coalesced, quad-broadcast)
    float y2r[4];
    #pragma unroll
    for (int ct = 0; ct < 4; ++ct)
      y2r[ct] = y2[(size_t)b * M_ + m0 + ct * 16 + l15];

    #pragma unroll
    for (int ct = 0; ct < 4; ++ct) {
      f32x4 a[4];
      #pragma unroll
      for (int rt = 0; rt < 4; ++rt) a[rt] = xvv[rt];   // acc init = x2
      #pragma unroll
      for (int kb = 0; kb < 4; ++kb) {                  // R12-style interleave
        const int row = ct * 16 + l15;
        const int pcB = (kb * 4 + quad) ^ l15;          // swizzled chunk
        bf16x8 bfr = *(const bf16x8*)((const char*)ys + d + row * 256 + pcB * 16);
        #pragma unroll
        for (int rt = 0; rt < 4; ++rt)
          a[rt] = __builtin_amdgcn_mfma_f32_16x16x32_bf16(afrag[kb][rt], bfr, a[rt], 0, 0, 0);
      }
      // epilogue (R13-proven): s = d^2, row-min partials in-register;
      // col-min: fold 16 regs, 2x shfl_xor folds quads -> wave min -> atomicMin
      float yv = y2r[ct];
      float c[4];
      #pragma unroll
      for (int rt = 0; rt < 4; ++rt) {
        float s0 = a[rt][0] + yv; rmin2[rt][0] = fminf(rmin2[rt][0], s0);
        float s1 = a[rt][1] + yv; rmin2[rt][1] = fminf(rmin2[rt][1], s1);
        float s2 = a[rt][2] + yv; rmin2[rt][2] = fminf(rmin2[rt][2], s2);
        float s3 = a[rt][3] + yv; rmin2[rt][3] = fminf(rmin2[rt][3], s3);
        c[rt] = fminf(fminf(s0, s1), fminf(s2, s3));
      }
      float cm = fminf(fminf(c[0], c[1]), fminf(c[2], c[3]));
      cm = fminf(cm, __shfl_xor(cm, 16, 64));
      cm = fminf(cm, __shfl_xor(cm, 32, 64));
      if (quad == 0)
        atomicMin((int*)(colmin + (size_t)b * M_ + m0 + ct * 16 + l15),
                  __float_as_int(cm));
    }
  }

  // Row mins over this chunk: reduce across 16 col-lanes, then atomicMin.
  #pragma unroll
  for (int rt = 0; rt < 4; ++rt) {
    #pragma unroll
    for (int r = 0; r < 4; ++r) {
      float v = rmin2[rt][r];
      v = fminf(v, __shfl_xor(v, 1, 64));
      v = fminf(v, __shfl_xor(v, 2, 64));
      v = fminf(v, __shfl_xor(v, 4, 64));
      v = fminf(v, __shfl_xor(v, 8, 64));
      if (l15 == 0)
        atomicMin((int*)(rowmin + (size_t)b * N_ + n0 + wave * 64 + rt * 16 + quad * 4 + r),
                  __float_as_int(v));
    }
  }

  // ---- completion protocol: last finishing block does the final reduce ----
  __threadfence();                 // release this thread's atomics (device scope)
  __syncthreads();                 // all threads of block have fenced
  if (tid == 0) amLast = (atomicAdd(counter, 1) == GRID - 1);
  __syncthreads();
  if (amLast) {
    __threadfence();               // acquire: all 1024 blocks' atomics visible
    float s = 0.0f;
    for (int i = tid; i < 2 * B_ * N_; i += 256) {
      float v = __hip_atomic_load(minbuf + i, __ATOMIC_RELAXED,
                                  __HIP_MEMORY_SCOPE_AGENT);
      s += sqrtf(fmaxf(v, 0.0f));
    }
    #pragma unroll
    for (int m = 1; m < 64; m <<= 1) s += __shfl_xor(s, m, 64);
    if (lane == 0) red[wave] = s;
    __syncthreads();
    if (tid == 0)
      *out = (red[0] + red[1] + red[2] + red[3]) / (float)(B_ * N_);
  }
}

extern "C" void kernel_launch(void* const* d_in, const int* in_sizes, int n_in,
                              void* d_out, int out_size, void* d_ws, size_t ws_size,
                              hipStream_t stream)
{
  const float* x = (const float*)d_in[0];
  const float* y = (const float*)d_in[1];
  char* ws = (char*)d_ws;

  unsigned short* yb = (unsigned short*)(ws);               // 8 MB
  float* y2     = (float*)(ws + (8u << 20));                // 128 KB
  float* minbuf = (float*)(ws + (8u << 20) + (1u << 17));   // 256 KB (rowmin++colmin)
  int*   cnt    = (int*)  (ws + (8u << 20) + (3u << 17));   // 4 B
  float* outf = (float*)d_out;

  prep_y<<<(B_ * M_) / 8, 256, 0, stream>>>(y, yb, y2, minbuf, cnt);

  chamfer<<<GRID, 256, 0, stream>>>(x, yb, y2, minbuf, cnt, outf);
}

// Round 6
// 199.516 us; speedup vs baseline: 1.2979x; 1.2979x over previous
//
#include <hip/hip_runtime.h>
#include <cstdint>

// Chamfer distance, B=8, N=M=4096, D=128, f32 in, scalar f32 out.
// R18: R17's 200us chamfer was ~55us of work + ~145us serial tail: the
// last-block reduce used 256 __hip_atomic_load(AGENT)/thread -- uncached,
// unbatchable, ~1200cy each, one block running alone (counters: all rates
// diluted 3.6x, occupancy 12%). Fix: canonical rocPRIM last-block pattern --
// release fence + counter; last block acquire-fences (buffer_inv makes the
// device-coherence-point atomicMin results visible) then PLAIN float4 loads
// of the 256KB minbuf (64 vec loads/thread, pipelined) -> sqrt/sum -> store.
// Main phase byte-identical to R17 (R13 proved the atomicMin scheme ~55us).
// Workspace: yb(8M) y2(128K) minbuf(256K) counter(4B).

#define B_   8
#define N_   4096
#define M_   4096
#define D_   128
#define TPB  8               // y-tiles (64 cols) per block -> 512-col chunk
#define ROWS_PB 256          // x-rows per block = 4 waves * 64
#define XG   (N_ / ROWS_PB)  // 16 x-groups
#define CHUNKS (M_ / (TPB * 64))   // 8 y-chunks
#define GRID (B_ * XG * CHUNKS)    // 1024 blocks

typedef __bf16 bf16x8 __attribute__((ext_vector_type(8)));
typedef float  f32x4  __attribute__((ext_vector_type(4)));
typedef unsigned int u32;

static __device__ __forceinline__ unsigned short f2bf(float f) {
  unsigned u = __float_as_uint(f);
  u += 0x7FFFu + ((u >> 16) & 1u);   // round-to-nearest-even
  return (unsigned short)(u >> 16);
}
static __device__ __forceinline__ u32 pk2(float a, float b) {
  return (u32)f2bf(a) | ((u32)f2bf(b) << 16);
}
static __device__ __forceinline__ void gld16(void* lds, const void* g) {
  __builtin_amdgcn_global_load_lds(
      (const __attribute__((address_space(1))) void*)g,
      (__attribute__((address_space(3))) void*)lds, 16, 0, 0);
}

// prep_y: wave handles 2 y-rows (32 lanes x float4). yb = bf16(y), y2 fp32.
// Also: minbuf[0..2*B*N) = +INF (rowmin ++ colmin), *counter = 0.
__global__ __launch_bounds__(256) void prep_y(
    const float* __restrict__ y, unsigned short* __restrict__ yb,
    float* __restrict__ y2, float* __restrict__ minbuf, int* __restrict__ counter)
{
  const int flat = blockIdx.x * 256 + threadIdx.x;
  if (flat < 2 * B_ * N_) minbuf[flat] = __uint_as_float(0x7F800000u);
  if (flat == 0) *counter = 0;

  int gw   = flat >> 6;                      // wave id 0..16383
  int lane = threadIdx.x & 63;
  int half = lane >> 5, sub = lane & 31;
  int row  = gw * 2 + half;                  // 0 .. B*M-1
  size_t base = (size_t)row * D_ + sub * 4;
  float4 v = *(const float4*)(y + base);
  u32 p0 = pk2(v.x, v.y);
  u32 p1 = pk2(v.z, v.w);
  *(uint2*)(yb + base) = make_uint2(p0, p1);
  float s = v.x * v.x + v.y * v.y + v.z * v.z + v.w * v.w;
  #pragma unroll
  for (int m = 1; m < 32; m <<= 1) s += __shfl_xor(s, m, 64);
  if (sub == 0) y2[row] = s;
}

// Fragment layouts (HW-verified):
//   A/B operand: lane holds elems [row=lane&15][k=(lane>>4)*8 + 0..7]
//   C/D:         lane reg r holds [row=(lane>>4)*4+r][col=lane&15]
// acc init = x2_i (afrag holds bf16(-2x)), so a = x2_i - 2<x,y>; s = a + y2_j.
// LDS y layout: row r (256B), logical 16B-chunk c at physical chunk c^(r&15).
__global__ __launch_bounds__(256) void chamfer(
    const float* __restrict__ x, const unsigned short* __restrict__ yb,
    const float* __restrict__ y2, float* __restrict__ minbuf,
    int* __restrict__ counter, float* __restrict__ out)
{
  __shared__ unsigned short ys[2 * 8192];    // two 16 KB swizzled y-tiles ONLY
  __shared__ int amLast;
  __shared__ float red[4];

  float* rowmin = minbuf;                    // [B*N]
  float* colmin = minbuf + B_ * N_;          // [B*M]

  const int tid  = threadIdx.x;
  const int wave = tid >> 6;                 // 0..3
  const int lane = tid & 63;
  const int quad = lane >> 4;
  const int l15  = lane & 15;

  const int id    = blockIdx.x;        // 0..1023
  const int b     = id & 7;
  const int xg    = (id >> 3) & 15;
  const int chunk = id >> 7;           // 0..7
  const int n0    = xg * ROWS_PB;
  const int mc0   = chunk * (TPB * 64);

  // DMA: 16KB tile, 4 gld16/lane: instr i covers bytes (wave*4+i)*1024+lane*16.
  int srcoff[4], ldsoff[4];
  #pragma unroll
  for (int i = 0; i < 4; ++i) {
    int p  = (wave * 4 + i) * 1024 + lane * 16;
    int r  = p >> 8;                 // y row 0..63
    int pc = (p >> 4) & 15;          // physical chunk
    int c  = pc ^ (r & 15);          // logical chunk
    srcoff[i] = r * D_ + c * 8;      // elements
    ldsoff[i] = (wave * 4 + i) * 1024;
  }

  // preload tile 0
  {
    const unsigned short* src = yb + ((size_t)b * M_ + mc0) * D_;
    #pragma unroll
    for (int i = 0; i < 4; ++i) gld16((char*)ys + ldsoff[i], src + srcoff[i]);
  }

  // prologue: x panel f32 -> afrag(bf16 of -2x) + x2 via quad folds (R16-proven)
  bf16x8 afrag[4][4];   // [kb][rt]
  f32x4 xvv[4];
  {
    float x2row[4];
    #pragma unroll
    for (int rt = 0; rt < 4; ++rt) {
      const float* xs = x + (size_t)(b * N_ + n0 + wave * 64 + rt * 16 + l15) * D_ + quad * 8;
      float p = 0.0f;
      #pragma unroll
      for (int kb = 0; kb < 4; ++kb) {
        float4 u0 = *(const float4*)(xs + kb * 32);
        float4 u1 = *(const float4*)(xs + kb * 32 + 4);
        p += u0.x*u0.x + u0.y*u0.y + u0.z*u0.z + u0.w*u0.w
           + u1.x*u1.x + u1.y*u1.y + u1.z*u1.z + u1.w*u1.w;
        union { u32 w[4]; bf16x8 v; } tt;
        tt.w[0] = pk2(-2.f*u0.x, -2.f*u0.y);
        tt.w[1] = pk2(-2.f*u0.z, -2.f*u0.w);
        tt.w[2] = pk2(-2.f*u1.x, -2.f*u1.y);
        tt.w[3] = pk2(-2.f*u1.z, -2.f*u1.w);
        afrag[kb][rt] = tt.v;
      }
      p += __shfl_xor(p, 16, 64);    // fold the 4 quads holding this row
      p += __shfl_xor(p, 32, 64);
      x2row[rt] = p;                 // = x2 of row rt*16 + l15
    }
    // redistribute to C/D layout: lane reg r needs row quad*4 + r
    #pragma unroll
    for (int rt = 0; rt < 4; ++rt)
      #pragma unroll
      for (int r = 0; r < 4; ++r)
        xvv[rt][r] = __shfl(x2row[rt], quad * 4 + r, 16);
  }

  const float FINF = __uint_as_float(0x7F800000u);
  float rmin2[4][4];
  #pragma unroll
  for (int rt = 0; rt < 4; ++rt)
    #pragma unroll
    for (int r = 0; r < 4; ++r) rmin2[rt][r] = FINF;

  #pragma unroll 1
  for (int t = 0; t < TPB; ++t) {
    const int m0 = mc0 + t * 64;
    const int d  = (t & 1) * 16384;    // current buffer byte offset
    __syncthreads();  // drains DMA for buf d (prefetch had a full iteration);
                      // fences prior-buffer reads

    if (t + 1 < TPB) {  // prefetch next tile into the other buffer ASAP
      const unsigned short* src = yb + ((size_t)b * M_ + m0 + 64) * D_;
      char* dst = (char*)ys + (16384 - d);
      #pragma unroll
      for (int i = 0; i < 4; ++i) gld16(dst + ldsoff[i], src + srcoff[i]);
    }

    // per-tile y^2: 4 per-lane scalars (16-lane coalesced, quad-broadcast)
    float y2r[4];
    #pragma unroll
    for (int ct = 0; ct < 4; ++ct)
      y2r[ct] = y2[(size_t)b * M_ + m0 + ct * 16 + l15];

    #pragma unroll
    for (int ct = 0; ct < 4; ++ct) {
      f32x4 a[4];
      #pragma unroll
      for (int rt = 0; rt < 4; ++rt) a[rt] = xvv[rt];   // acc init = x2
      #pragma unroll
      for (int kb = 0; kb < 4; ++kb) {                  // R12-style interleave
        const int row = ct * 16 + l15;
        const int pcB = (kb * 4 + quad) ^ l15;          // swizzled chunk
        bf16x8 bfr = *(const bf16x8*)((const char*)ys + d + row * 256 + pcB * 16);
        #pragma unroll
        for (int rt = 0; rt < 4; ++rt)
          a[rt] = __builtin_amdgcn_mfma_f32_16x16x32_bf16(afrag[kb][rt], bfr, a[rt], 0, 0, 0);
      }
      // epilogue (R13-proven): s = d^2, row-min partials in-register;
      // col-min: fold 16 regs, 2x shfl_xor folds quads -> wave min -> atomicMin
      float yv = y2r[ct];
      float c[4];
      #pragma unroll
      for (int rt = 0; rt < 4; ++rt) {
        float s0 = a[rt][0] + yv; rmin2[rt][0] = fminf(rmin2[rt][0], s0);
        float s1 = a[rt][1] + yv; rmin2[rt][1] = fminf(rmin2[rt][1], s1);
        float s2 = a[rt][2] + yv; rmin2[rt][2] = fminf(rmin2[rt][2], s2);
        float s3 = a[rt][3] + yv; rmin2[rt][3] = fminf(rmin2[rt][3], s3);
        c[rt] = fminf(fminf(s0, s1), fminf(s2, s3));
      }
      float cm = fminf(fminf(c[0], c[1]), fminf(c[2], c[3]));
      cm = fminf(cm, __shfl_xor(cm, 16, 64));
      cm = fminf(cm, __shfl_xor(cm, 32, 64));
      if (quad == 0)
        atomicMin((int*)(colmin + (size_t)b * M_ + m0 + ct * 16 + l15),
                  __float_as_int(cm));
    }
  }

  // Row mins over this chunk: reduce across 16 col-lanes, then atomicMin.
  #pragma unroll
  for (int rt = 0; rt < 4; ++rt) {
    #pragma unroll
    for (int r = 0; r < 4; ++r) {
      float v = rmin2[rt][r];
      v = fminf(v, __shfl_xor(v, 1, 64));
      v = fminf(v, __shfl_xor(v, 2, 64));
      v = fminf(v, __shfl_xor(v, 4, 64));
      v = fminf(v, __shfl_xor(v, 8, 64));
      if (l15 == 0)
        atomicMin((int*)(rowmin + (size_t)b * N_ + n0 + wave * 64 + rt * 16 + quad * 4 + r),
                  __float_as_int(v));
    }
  }

  // ---- completion protocol (rocPRIM/CUB last-block pattern) ----
  __threadfence();                 // release: this block's atomics visible
  __syncthreads();                 // whole block has fenced
  if (tid == 0) amLast = (atomicAdd(counter, 1) == GRID - 1);
  __syncthreads();
  if (amLast) {
    __threadfence();               // acquire: invalidate stale cache lines;
                                   // all 1024 blocks' atomicMins now visible
    const float4* mb4 = (const float4*)minbuf;   // plain cached vector loads
    float s = 0.0f;
    #pragma unroll 4
    for (int i = tid; i < (2 * B_ * N_) / 4; i += 256) {
      float4 v = mb4[i];
      s += sqrtf(fmaxf(v.x, 0.0f)) + sqrtf(fmaxf(v.y, 0.0f))
         + sqrtf(fmaxf(v.z, 0.0f)) + sqrtf(fmaxf(v.w, 0.0f));
    }
    #pragma unroll
    for (int m = 1; m < 64; m <<= 1) s += __shfl_xor(s, m, 64);
    if (lane == 0) red[wave] = s;
    __syncthreads();
    if (tid == 0)
      *out = (red[0] + red[1] + red[2] + red[3]) / (float)(B_ * N_);
  }
}

extern "C" void kernel_launch(void* const* d_in, const int* in_sizes, int n_in,
                              void* d_out, int out_size, void* d_ws, size_t ws_size,
                              hipStream_t stream)
{
  const float* x = (const float*)d_in[0];
  const float* y = (const float*)d_in[1];
  char* ws = (char*)d_ws;

  unsigned short* yb = (unsigned short*)(ws);               // 8 MB
  float* y2     = (float*)(ws + (8u << 20));                // 128 KB
  float* minbuf = (float*)(ws + (8u << 20) + (1u << 17));   // 256 KB (rowmin++colmin)
  int*   cnt    = (int*)  (ws + (8u << 20) + (3u << 17));   // 4 B
  float* outf = (float*)d_out;

  prep_y<<<(B_ * M_) / 8, 256, 0, stream>>>(y, yb, y2, minbuf, cnt);

  chamfer<<<GRID, 256, 0, stream>>>(x, yb, y2, minbuf, cnt, outf);
}

// Round 7
// 145.065 us; speedup vs baseline: 1.7851x; 1.3754x over previous
//
#include <hip/hip_runtime.h>
#include <cstdint>

// Chamfer distance, B=8, N=M=4096, D=128, f32 in, scalar f32 out.
// R19: fence-free completion protocol. R18's chamfer was 135us vs R13's 55.6
// for the same loop+atomicMin: prime suspect is the per-wave release
// __threadfence() (buffer_wbl2 = full-L2 writeback x 4096 waves). It is also
// unnecessary: device-scope atomicMin is performed at the memory-side
// coherence point and ack'd before vmcnt drains -- __syncthreads() already
// waits vmcnt(0), so block-completion ordering needs NO cache writeback.
// Secondary suspect (f32 x-prologue) also removed: prep converts BOTH x and y
// (the original proven pass1), chamfer loads xb/x2 exactly like R12 (46.7us).
// Completion: syncthreads -> relaxed atomicAdd(counter) by tid0 -> last block
// does ONE acquire __threadfence (invalidate) -> plain float4 reduce of the
// 256KB minbuf -> plain store to out (harness pre-zeroes out; memset deleted).
// Workspace: xb(8M) yb(8M) x2(128K) y2(128K) minbuf(256K) counter(4B).

#define B_   8
#define N_   4096
#define M_   4096
#define D_   128
#define TPB  8               // y-tiles (64 cols) per block -> 512-col chunk
#define ROWS_PB 256          // x-rows per block = 4 waves * 64
#define XG   (N_ / ROWS_PB)  // 16 x-groups
#define CHUNKS (M_ / (TPB * 64))   // 8 y-chunks
#define GRID (B_ * XG * CHUNKS)    // 1024 blocks

typedef __bf16 bf16x8 __attribute__((ext_vector_type(8)));
typedef float  f32x4  __attribute__((ext_vector_type(4)));
typedef unsigned int u32;

static __device__ __forceinline__ unsigned short f2bf(float f) {
  unsigned u = __float_as_uint(f);
  u += 0x7FFFu + ((u >> 16) & 1u);   // round-to-nearest-even
  return (unsigned short)(u >> 16);
}
static __device__ __forceinline__ void gld16(void* lds, const void* g) {
  __builtin_amdgcn_global_load_lds(
      (const __attribute__((address_space(1))) void*)g,
      (__attribute__((address_space(3))) void*)lds, 16, 0, 0);
}

// prep: wave handles 2 rows (32 lanes x float4 each). xb = bf16(-2x),
// yb = bf16(y), fp32 norms. Also seeds minbuf=+INF and counter=0.
__global__ __launch_bounds__(256) void prep(
    const float* __restrict__ x, const float* __restrict__ y,
    unsigned short* __restrict__ xb, unsigned short* __restrict__ yb,
    float* __restrict__ x2, float* __restrict__ y2,
    float* __restrict__ minbuf, int* __restrict__ counter)
{
  const int ROWS = B_ * N_;
  const int flat = blockIdx.x * 256 + threadIdx.x;
  if (flat < 2 * B_ * N_) minbuf[flat] = __uint_as_float(0x7F800000u);
  if (flat == 0) *counter = 0;

  int gw   = flat >> 6;                      // wave id
  int lane = threadIdx.x & 63;
  int half = lane >> 5, sub = lane & 31;
  int row2 = gw * 2 + half;                  // 0 .. 2*ROWS-1 (x rows then y rows)
  bool isx = row2 < ROWS;
  const float* src; unsigned short* dst; float* nrm; int row;
  if (isx) { src = x; dst = xb; nrm = x2; row = row2; }
  else     { src = y; dst = yb; nrm = y2; row = row2 - ROWS; }
  size_t base = (size_t)row * D_ + sub * 4;
  float4 v = *(const float4*)(src + base);
  float sx = isx ? -2.0f : 1.0f;
  u32 p0 = (u32)f2bf(sx * v.x) | ((u32)f2bf(sx * v.y) << 16);
  u32 p1 = (u32)f2bf(sx * v.z) | ((u32)f2bf(sx * v.w) << 16);
  *(uint2*)(dst + base) = make_uint2(p0, p1);
  float s = v.x * v.x + v.y * v.y + v.z * v.z + v.w * v.w;
  #pragma unroll
  for (int m = 1; m < 32; m <<= 1) s += __shfl_xor(s, m, 64);
  if (sub == 0) nrm[row] = s;
}

// Fragment layouts (HW-verified):
//   A/B operand: lane holds elems [row=lane&15][k=(lane>>4)*8 + 0..7]
//   C/D:         lane reg r holds [row=(lane>>4)*4+r][col=lane&15]
// acc init = x2_i (xb holds bf16(-2x)), so a = x2_i - 2<x,y>; s = a + y2_j.
// LDS y layout: row r (256B), logical 16B-chunk c at physical chunk c^(r&15).
__global__ __launch_bounds__(256) void chamfer(
    const unsigned short* __restrict__ xb, const unsigned short* __restrict__ yb,
    const float* __restrict__ x2, const float* __restrict__ y2,
    float* __restrict__ minbuf, int* __restrict__ counter,
    float* __restrict__ out)
{
  __shared__ unsigned short ys[2 * 8192];    // two 16 KB swizzled y-tiles ONLY
  __shared__ int amLast;
  __shared__ float red[4];

  float* rowmin = minbuf;                    // [B*N]
  float* colmin = minbuf + B_ * N_;          // [B*M]

  const int tid  = threadIdx.x;
  const int wave = tid >> 6;                 // 0..3
  const int lane = tid & 63;
  const int quad = lane >> 4;
  const int l15  = lane & 15;

  const int id    = blockIdx.x;        // 0..1023
  const int b     = id & 7;
  const int xg    = (id >> 3) & 15;
  const int chunk = id >> 7;           // 0..7
  const int n0    = xg * ROWS_PB;
  const int mc0   = chunk * (TPB * 64);

  // DMA: 16KB tile, 4 gld16/lane: instr i covers bytes (wave*4+i)*1024+lane*16.
  int srcoff[4], ldsoff[4];
  #pragma unroll
  for (int i = 0; i < 4; ++i) {
    int p  = (wave * 4 + i) * 1024 + lane * 16;
    int r  = p >> 8;                 // y row 0..63
    int pc = (p >> 4) & 15;          // physical chunk
    int c  = pc ^ (r & 15);          // logical chunk
    srcoff[i] = r * D_ + c * 8;      // elements
    ldsoff[i] = (wave * 4 + i) * 1024;
  }

  // preload tile 0
  {
    const unsigned short* src = yb + ((size_t)b * M_ + mc0) * D_;
    #pragma unroll
    for (int i = 0; i < 4; ++i) gld16((char*)ys + ldsoff[i], src + srcoff[i]);
  }

  // A fragments: direct global->register, rows n0 + wave*64 + rt*16 + l15.
  bf16x8 afrag[4][4];   // [kb][rt]
  const size_t xrow0 = (size_t)b * N_ + n0 + wave * 64;
  #pragma unroll
  for (int kb = 0; kb < 4; ++kb)
    #pragma unroll
    for (int rt = 0; rt < 4; ++rt)
      afrag[kb][rt] = *(const bf16x8*)(xb + (xrow0 + rt * 16 + l15) * D_ + kb * 32 + quad * 8);

  // x2 for this wave's 16 output rows (t-invariant), as f32x4 for acc init
  f32x4 xvv[4];
  #pragma unroll
  for (int rt = 0; rt < 4; ++rt)
    #pragma unroll
    for (int r = 0; r < 4; ++r)
      xvv[rt][r] = x2[(size_t)b * N_ + n0 + wave * 64 + rt * 16 + quad * 4 + r];

  const float FINF = __uint_as_float(0x7F800000u);
  float rmin2[4][4];
  #pragma unroll
  for (int rt = 0; rt < 4; ++rt)
    #pragma unroll
    for (int r = 0; r < 4; ++r) rmin2[rt][r] = FINF;

  #pragma unroll 1
  for (int t = 0; t < TPB; ++t) {
    const int m0 = mc0 + t * 64;
    const int d  = (t & 1) * 16384;    // current buffer byte offset
    __syncthreads();  // drains DMA for buf d (prefetch had a full iteration);
                      // fences prior-buffer reads

    if (t + 1 < TPB) {  // prefetch next tile into the other buffer ASAP
      const unsigned short* src = yb + ((size_t)b * M_ + m0 + 64) * D_;
      char* dst = (char*)ys + (16384 - d);
      #pragma unroll
      for (int i = 0; i < 4; ++i) gld16(dst + ldsoff[i], src + srcoff[i]);
    }

    // per-tile y^2: 4 per-lane scalars (16-lane coalesced, quad-broadcast)
    float y2r[4];
    #pragma unroll
    for (int ct = 0; ct < 4; ++ct)
      y2r[ct] = y2[(size_t)b * M_ + m0 + ct * 16 + l15];

    #pragma unroll
    for (int ct = 0; ct < 4; ++ct) {
      f32x4 a[4];
      #pragma unroll
      for (int rt = 0; rt < 4; ++rt) a[rt] = xvv[rt];   // acc init = x2
      #pragma unroll
      for (int kb = 0; kb < 4; ++kb) {                  // R12-style interleave
        const int row = ct * 16 + l15;
        const int pcB = (kb * 4 + quad) ^ l15;          // swizzled chunk
        bf16x8 bfr = *(const bf16x8*)((const char*)ys + d + row * 256 + pcB * 16);
        #pragma unroll
        for (int rt = 0; rt < 4; ++rt)
          a[rt] = __builtin_amdgcn_mfma_f32_16x16x32_bf16(afrag[kb][rt], bfr, a[rt], 0, 0, 0);
      }
      // epilogue (R13-proven): s = d^2, row-min partials in-register;
      // col-min: fold 16 regs, 2x shfl_xor folds quads -> wave min -> atomicMin
      float yv = y2r[ct];
      float c[4];
      #pragma unroll
      for (int rt = 0; rt < 4; ++rt) {
        float s0 = a[rt][0] + yv; rmin2[rt][0] = fminf(rmin2[rt][0], s0);
        float s1 = a[rt][1] + yv; rmin2[rt][1] = fminf(rmin2[rt][1], s1);
        float s2 = a[rt][2] + yv; rmin2[rt][2] = fminf(rmin2[rt][2], s2);
        float s3 = a[rt][3] + yv; rmin2[rt][3] = fminf(rmin2[rt][3], s3);
        c[rt] = fminf(fminf(s0, s1), fminf(s2, s3));
      }
      float cm = fminf(fminf(c[0], c[1]), fminf(c[2], c[3]));
      cm = fminf(cm, __shfl_xor(cm, 16, 64));
      cm = fminf(cm, __shfl_xor(cm, 32, 64));
      if (quad == 0)
        atomicMin((int*)(colmin + (size_t)b * M_ + m0 + ct * 16 + l15),
                  __float_as_int(cm));
    }
  }

  // Row mins over this chunk: reduce across 16 col-lanes, then atomicMin.
  #pragma unroll
  for (int rt = 0; rt < 4; ++rt) {
    #pragma unroll
    for (int r = 0; r < 4; ++r) {
      float v = rmin2[rt][r];
      v = fminf(v, __shfl_xor(v, 1, 64));
      v = fminf(v, __shfl_xor(v, 2, 64));
      v = fminf(v, __shfl_xor(v, 4, 64));
      v = fminf(v, __shfl_xor(v, 8, 64));
      if (l15 == 0)
        atomicMin((int*)(rowmin + (size_t)b * N_ + n0 + wave * 64 + rt * 16 + quad * 4 + r),
                  __float_as_int(v));
    }
  }

  // ---- completion protocol, FENCE-FREE release ----
  // Device-scope atomicMin executes at the memory-side coherence point and is
  // ack'd before vmcnt decrements; __syncthreads() waits vmcnt(0) for the
  // whole block. So after this barrier, every atomicMin of this block is
  // globally complete -- no buffer_wbl2 (threadfence) needed. (R18's per-wave
  // release threadfence = 4096x full-L2 writeback = the 75us regression.)
  __syncthreads();
  if (tid == 0)
    amLast = (__hip_atomic_fetch_add(counter, 1, __ATOMIC_RELAXED,
                                     __HIP_MEMORY_SCOPE_AGENT) == GRID - 1);
  __syncthreads();
  if (amLast) {
    __threadfence();               // acquire (once, 4 waves): invalidate L1/L2
                                   // so plain loads see the coherence point
    const float4* mb4 = (const float4*)minbuf;   // plain cached vector loads
    float s = 0.0f;
    #pragma unroll 4
    for (int i = tid; i < (2 * B_ * N_) / 4; i += 256) {
      float4 v = mb4[i];
      s += sqrtf(fmaxf(v.x, 0.0f)) + sqrtf(fmaxf(v.y, 0.0f))
         + sqrtf(fmaxf(v.z, 0.0f)) + sqrtf(fmaxf(v.w, 0.0f));
    }
    #pragma unroll
    for (int m = 1; m < 64; m <<= 1) s += __shfl_xor(s, m, 64);
    if (lane == 0) red[wave] = s;
    __syncthreads();
    if (tid == 0)
      *out = (red[0] + red[1] + red[2] + red[3]) / (float)(B_ * N_);
  }
}

extern "C" void kernel_launch(void* const* d_in, const int* in_sizes, int n_in,
                              void* d_out, int out_size, void* d_ws, size_t ws_size,
                              hipStream_t stream)
{
  const float* x = (const float*)d_in[0];
  const float* y = (const float*)d_in[1];
  char* ws = (char*)d_ws;

  unsigned short* xb = (unsigned short*)(ws);               // 8 MB
  unsigned short* yb = (unsigned short*)(ws + (8u << 20));  // 8 MB
  float* x2     = (float*)(ws + (16u << 20));               // 128 KB
  float* y2     = (float*)(ws + (16u << 20) + (1u << 17));  // 128 KB
  float* minbuf = (float*)(ws + (16u << 20) + (2u << 17));  // 256 KB (rowmin++colmin)
  int*   cnt    = (int*)  (ws + (16u << 20) + (4u << 17));  // 4 B
  float* outf = (float*)d_out;

  // no memset dispatch: harness pre-zeroes out, and the last block
  // plain-stores the final value anyway.

  prep<<<(B_ * N_) / 4, 256, 0, stream>>>(x, y, xb, yb, x2, y2, minbuf, cnt);

  chamfer<<<GRID, 256, 0, stream>>>(xb, yb, x2, y2, minbuf, cnt, outf);
}